// Round 6
// baseline (196.745 us; speedup 1.0000x reference)
//
#include <hip/hip_runtime.h>
#include <hip/hip_bf16.h>
#include <math.h>

// MoE top-2: B=4,S=2048,H=1024,E=8,K=2. fp32 in/out, f16 MFMA compute.
#define TOK 8192
#define HD 1024
#define NE 8
#define SLOTS 18432     // 16384 + per-expert 256-pad (BM=256 tiles)
#define NGRP 512        // 16-token scatter groups
#define GRPSZ 16

typedef _Float16 half8 __attribute__((ext_vector_type(8)));
typedef _Float16 half4v __attribute__((ext_vector_type(4)));
typedef float floatx4 __attribute__((ext_vector_type(4)));

#define WAIT_VMCNT(N) asm volatile("s_waitcnt vmcnt(" #N ")" ::: "memory")
#define WAIT_LGKM0()  asm volatile("s_waitcnt lgkmcnt(0)" ::: "memory")
#define MEMFENCE()    asm volatile("" ::: "memory")

struct CTrue  { static constexpr bool value = true;  };
struct CFalse { static constexpr bool value = false; };

// ---- Fused score + weight-convert (block-role split) ----
__global__ __launch_bounds__(256) void score_cvt(
    const float* __restrict__ x,
    const float* __restrict__ rw,
    const float* __restrict__ rb,
    const float* __restrict__ ew,
    _Float16* __restrict__ xh,
    _Float16* __restrict__ wh,
    int* __restrict__ epair,
    float* __restrict__ w1out,
    int* __restrict__ hist) {          // [NE][NGRP]
  const int tid = threadIdx.x;
  const int blk = blockIdx.x;
  if (blk >= NGRP) {
    const int g = (blk - NGRP) * 256 + tid;
    const float4* src = (const float4*)ew;
    half4v* dst = (half4v*)wh;
#pragma unroll
    for (int j = 0; j < 4; ++j) {
      float4 v = src[g + 524288 * j];
      half4v h = {(_Float16)v.x, (_Float16)v.y, (_Float16)v.z, (_Float16)v.w};
      dst[g + 524288 * j] = h;
    }
    return;
  }
  const int lane = tid & 63;
  const int wid = tid >> 6;
  __shared__ int hcnt[NE];
  if (tid < NE) hcnt[tid] = 0;
  __syncthreads();

#pragma unroll
  for (int i = 0; i < 4; ++i) {
    const int t = blk * GRPSZ + wid * 4 + i;
    const float4* xp = (const float4*)(x + (size_t)t * HD);
    float4 xr[4];
#pragma unroll
    for (int k = 0; k < 4; ++k) xr[k] = xp[lane + 64 * k];
    _Float16* xo = xh + (size_t)t * HD;
#pragma unroll
    for (int k = 0; k < 4; ++k) {
      half4v h = {(_Float16)xr[k].x, (_Float16)xr[k].y,
                  (_Float16)xr[k].z, (_Float16)xr[k].w};
      *(half4v*)(xo + (lane + 64 * k) * 4) = h;
    }
    float sc[NE];
#pragma unroll
    for (int e = 0; e < NE; ++e) {
      const float4* wp = (const float4*)(rw + e * HD);
      float a = 0.f;
#pragma unroll
      for (int k = 0; k < 4; ++k) {
        float4 w = wp[lane + 64 * k];
        a += xr[k].x * w.x + xr[k].y * w.y + xr[k].z * w.z + xr[k].w * w.w;
      }
#pragma unroll
      for (int off = 32; off > 0; off >>= 1) a += __shfl_xor(a, off);
      sc[e] = a + rb[e];
    }
    // top-2, strict > (ties -> lowest index, matches jax.lax.top_k)
    float b1 = sc[0]; int e1 = 0;
#pragma unroll
    for (int e = 1; e < NE; ++e) if (sc[e] > b1) { b1 = sc[e]; e1 = e; }
    float b2 = -1e30f; int e2 = 0;
#pragma unroll
    for (int e = 0; e < NE; ++e) { if (e != e1 && sc[e] > b2) { b2 = sc[e]; e2 = e; } }
    if (lane == 0) {
      epair[t] = e1 | (e2 << 8);
      w1out[t] = 1.f / (1.f + expf(b2 - b1));  // renormalized top-2 softmax
      atomicAdd(&hcnt[e1], 1);
      atomicAdd(&hcnt[e2], 1);
    }
  }
  __syncthreads();
  if (tid < NE) hist[tid * NGRP + blk] = hcnt[tid];
}

// ---- Scatter: each block recomputes its prefix from hist (no global sync) --
__global__ __launch_bounds__(256) void moe_scatter(
    const int* __restrict__ hist,
    const int* __restrict__ epair,
    const float* __restrict__ w1in,
    int* __restrict__ cntp,
    int* __restrict__ basep,
    int* __restrict__ tok_list,
    float* __restrict__ tok_w,
    int* __restrict__ slot_of) {
  const int tid = threadIdx.x;
  const int blk = blockIdx.x;
  __shared__ int pre_s[NE], tot_s[NE], alloc_s[NE];
  {
    const int e = tid >> 5;
    const int sl = tid & 31;
    int p = 0, tt = 0;
#pragma unroll
    for (int j = 0; j < 16; ++j) {
      int g = sl + 32 * j;
      int h = hist[e * NGRP + g];
      tt += h;
      p += (g < blk) ? h : 0;
    }
#pragma unroll
    for (int off = 16; off > 0; off >>= 1) {
      p += __shfl_xor(p, off);
      tt += __shfl_xor(tt, off);
    }
    if (sl == 0) { pre_s[e] = p; tot_s[e] = tt; }
  }
  __syncthreads();
  if (tid == 0) {
    int b = 0;
    for (int e = 0; e < NE; ++e) {
      alloc_s[e] = b + pre_s[e];
      if (blk == 0) { cntp[e * 64] = tot_s[e]; basep[e] = b; }
      b += (tot_s[e] + 255) & ~255;   // 256-pad: BM=256 tiles never straddle
    }
  }
  __syncthreads();
  if (tid < GRPSZ) {
    const int t = blk * GRPSZ + tid;
    int ep = epair[t];
    int e1 = ep & 0xff, e2 = ep >> 8;
    float w1 = w1in[t];
    int s1 = atomicAdd(&alloc_s[e1], 1);
    tok_list[s1] = t; tok_w[s1] = w1; slot_of[2 * t] = s1;
    int s2 = atomicAdd(&alloc_s[e2], 1);
    tok_list[s2] = t; tok_w[s2] = 1.f - w1; slot_of[2 * t + 1] = s2;
  }
}

// ---- Grouped expert GEMM: 256x256, BK=64, 8-wave FAITHFUL 8-phase port.
// R3/R4 failure analysis: ds_reads issued AFTER the phase barrier (full read
// latency exposed pre-MFMA) + only ONE barrier/phase (no role-split lockstep,
// setprio useless) + R4 drained vmcnt(0). This port keeps the template's
// three load-bearing properties:
//  (1) ds_reads issued BEFORE barrier-A (latency overlaps barrier arrival),
//  (2) TWO barriers/phase (issue-section || MFMA-section lockstep),
//  (3) counted trailing vmcnt(4) only (waits target loads >=2 phases old;
//      never 0 until the tail peel 4->2->0).
// Wave geometry spans both halves (rows wm*64 & +128; cols wn*32 & +128) so
// every wave's half-tile dependency timing is uniform -> per-wave vmcnt
// bookkeeping is valid. Stage order per tile: A0@p0, B0@p1, B1@p2, A1@p3.
// Reads: p0=A-low+B-low(12), p1=B-high(4), p2=A-high(8), p3=none.
// Grid (4, NE*64): XCD=(4*mt+x)%8 -> uniform, balanced (no expert pinning;
// R5 proved traffic is not the limiter, so balance > locality).
// 3-bit XOR chunk swizzle (0 conflicts measured all rounds).
template <int EPI>
__global__ __launch_bounds__(512, 2) void moe_gemm(
    const _Float16* __restrict__ Ah, const _Float16* __restrict__ Bh,
    const float* __restrict__ eb,
    const int* __restrict__ cntp, const int* __restrict__ base,
    const int* __restrict__ tok_list, const float* __restrict__ tok_w,
    _Float16* __restrict__ scratch, float* __restrict__ out) {
  const int e = blockIdx.y >> 6;           // expert
  const int mt = blockIdx.y & 63;          // m-tile (worst case 16384/256)
  const int ce = cntp[e * 64];
  const int m0 = mt << 8;
  if (m0 >= ce) return;
  const int nb = blockIdx.x << 8;          // n-tile * 256
  const int sbase = base[e];
  const int tid = threadIdx.x;
  const int lane = tid & 63;
  const int wid = tid >> 6;                // 0..7
  const int wm = wid >> 2, wn = wid & 3;   // rows {wm*64,+128}, cols {wn*32,+128}

  __shared__ _Float16 A_s[2][256 * 64];
  __shared__ _Float16 B_s[2][256 * 64];
  __shared__ int tok_s[256];
  __shared__ float w_s[256];

  if (tid < 256) {
    int tk = 0; float w = 0.f;
    if (m0 + tid < ce) { tk = tok_list[sbase + m0 + tid]; w = tok_w[sbase + m0 + tid]; }
    tok_s[tid] = tk; w_s[tid] = w;
  }
  __syncthreads();   // drains vmcnt -> clean counter before pipeline

  floatx4 acc[8][4];
  floatx4 zero = {0.f, 0.f, 0.f, 0.f};
#pragma unroll
  for (int i = 0; i < 8; ++i)
#pragma unroll
    for (int j = 0; j < 4; ++j) acc[i][j] = zero;

  const int wbase = e * HD * HD;
  // staging: half-tile = 128 rows; 2 gload_lds/wave (each: 8 rows x 8 chunks,
  // 16B/lane). u = half*2 + c; wave's rows: half*128 + c*64 + wid*8 + rloc.
  const int rloc = lane >> 3, sub = lane & 7;
  const int g8 = (sub ^ rloc) * 8;         // (row&7)==rloc for our rows
  int agoff[4], bgoff[4];
#pragma unroll
  for (int u = 0; u < 4; ++u) {
    const int row = (u >> 1) * 128 + (u & 1) * 64 + wid * 8 + rloc;
    agoff[u] = tok_s[row] * HD + g8;
    bgoff[u] = wbase + (nb + row) * HD + g8;
  }
  const int l15 = lane & 15, q4 = lane >> 4;
  const int ck0 = (q4 ^ (l15 & 7)) * 8;
  const int ck1 = ((4 + q4) ^ (l15 & 7)) * 8;

  auto gl = [](const _Float16* src, _Float16* dst) {
    __builtin_amdgcn_global_load_lds(
        (const __attribute__((address_space(1))) unsigned int*)src,
        (__attribute__((address_space(3))) unsigned int*)dst, 16, 0, 0);
  };
  auto stageA = [&](int uh, int buf, int k0) {
#pragma unroll
    for (int c = 0; c < 2; ++c) {
      const int r0 = uh * 128 + c * 64 + wid * 8;
      gl(Ah + agoff[uh * 2 + c] + k0, &A_s[buf][r0 * 64]);
    }
  };
  auto stageB = [&](int uh, int buf, int k0) {
#pragma unroll
    for (int c = 0; c < 2; ++c) {
      const int r0 = uh * 128 + c * 64 + wid * 8;
      gl(Bh + bgoff[uh * 2 + c] + k0, &B_s[buf][r0 * 64]);
    }
  };
  auto mf = [](half8 a, half8 b, floatx4 c) {
    return __builtin_amdgcn_mfma_f32_16x16x32_f16(a, b, c, 0, 0, 0);
  };

  // prologue: tile 0, canonical order A0,B0,B1,A1; retire A0,B0 (vmcnt 8->4)
  stageA(0, 0, 0);
  stageB(0, 0, 0);
  stageB(1, 0, 0);
  stageA(1, 0, 0);
  WAIT_VMCNT(4);
  __builtin_amdgcn_s_barrier();

  auto run_tile = [&](int t, auto lastc) {
    constexpr bool LAST = decltype(lastc)::value;
    const int cur = t & 1, nxt = cur ^ 1;
    const int kn = (t + 1) * 64;
    half8 a0[4][2], a1[4][2], b01[2][2], b23[2][2];

    // -- P0: read A-low + B-low; stage A0(t+1); MFMA Q(0,0); trail vm(4) --
#pragma unroll
    for (int i = 0; i < 4; ++i) {
      const int r = (wm * 64 + i * 16 + l15) * 64;
      a0[i][0] = *(const half8*)&A_s[cur][r + ck0];
      a0[i][1] = *(const half8*)&A_s[cur][r + ck1];
    }
#pragma unroll
    for (int j = 0; j < 2; ++j) {
      const int r = (wn * 32 + j * 16 + l15) * 64;
      b01[j][0] = *(const half8*)&B_s[cur][r + ck0];
      b01[j][1] = *(const half8*)&B_s[cur][r + ck1];
    }
    if constexpr (!LAST) stageA(0, nxt, kn);
    MEMFENCE();
    __builtin_amdgcn_s_barrier();
    WAIT_LGKM0();
    __builtin_amdgcn_s_setprio(1);
#pragma unroll
    for (int i = 0; i < 4; ++i)
#pragma unroll
      for (int j = 0; j < 2; ++j) {
        acc[i][j] = mf(a0[i][0], b01[j][0], acc[i][j]);
        acc[i][j] = mf(a0[i][1], b01[j][1], acc[i][j]);
      }
    __builtin_amdgcn_s_setprio(0);
    if constexpr (!LAST) { WAIT_VMCNT(4); } else { WAIT_VMCNT(2); }
    __builtin_amdgcn_s_barrier();

    // -- P1: read B-high; stage B0(t+1); MFMA Q(0,1); trail vm(4) --
#pragma unroll
    for (int j = 0; j < 2; ++j) {
      const int r = (128 + wn * 32 + j * 16 + l15) * 64;
      b23[j][0] = *(const half8*)&B_s[cur][r + ck0];
      b23[j][1] = *(const half8*)&B_s[cur][r + ck1];
    }
    if constexpr (!LAST) stageB(0, nxt, kn);
    MEMFENCE();
    __builtin_amdgcn_s_barrier();
    WAIT_LGKM0();
    __builtin_amdgcn_s_setprio(1);
#pragma unroll
    for (int i = 0; i < 4; ++i)
#pragma unroll
      for (int j = 0; j < 2; ++j) {
        acc[i][j + 2] = mf(a0[i][0], b23[j][0], acc[i][j + 2]);
        acc[i][j + 2] = mf(a0[i][1], b23[j][1], acc[i][j + 2]);
      }
    __builtin_amdgcn_s_setprio(0);
    if constexpr (!LAST) { WAIT_VMCNT(4); } else { WAIT_VMCNT(0); }
    __builtin_amdgcn_s_barrier();

    // -- P2: read A-high; stage B1(t+1); MFMA Q(1,1); no trail wait --
#pragma unroll
    for (int i = 0; i < 4; ++i) {
      const int r = (128 + wm * 64 + i * 16 + l15) * 64;
      a1[i][0] = *(const half8*)&A_s[cur][r + ck0];
      a1[i][1] = *(const half8*)&A_s[cur][r + ck1];
    }
    if constexpr (!LAST) stageB(1, nxt, kn);
    MEMFENCE();
    __builtin_amdgcn_s_barrier();
    WAIT_LGKM0();
    __builtin_amdgcn_s_setprio(1);
#pragma unroll
    for (int i = 0; i < 4; ++i)
#pragma unroll
      for (int j = 0; j < 2; ++j) {
        acc[i + 4][j + 2] = mf(a1[i][0], b23[j][0], acc[i + 4][j + 2]);
        acc[i + 4][j + 2] = mf(a1[i][1], b23[j][1], acc[i + 4][j + 2]);
      }
    __builtin_amdgcn_s_setprio(0);
    __builtin_amdgcn_s_barrier();

    // -- P3: no reads; stage A1(t+1); MFMA Q(1,0); trail vm(4) --
    if constexpr (!LAST) stageA(1, nxt, kn);
    MEMFENCE();
    __builtin_amdgcn_s_setprio(1);
#pragma unroll
    for (int i = 0; i < 4; ++i)
#pragma unroll
      for (int j = 0; j < 2; ++j) {
        acc[i + 4][j] = mf(a1[i][0], b01[j][0], acc[i + 4][j]);
        acc[i + 4][j] = mf(a1[i][1], b01[j][1], acc[i + 4][j]);
      }
    __builtin_amdgcn_s_setprio(0);
    if constexpr (!LAST) WAIT_VMCNT(4);
    __builtin_amdgcn_s_barrier();
  };

  for (int t = 0; t < 15; ++t) run_tile(t, CFalse{});
  run_tile(15, CTrue{});

  // epilogue: C/D layout col=lane&15, row=(lane>>4)*4+reg; wave tile is
  // split: row half from i>>2 (+128), col half from j>>1 (+128).
#pragma unroll
  for (int j = 0; j < 4; ++j) {
    const int col = nb + wn * 32 + (j & 1) * 16 + (j >> 1) * 128 + l15;
    const float bias = eb[e * HD + col];
#pragma unroll
    for (int i = 0; i < 8; ++i) {
      const int rbase = wm * 64 + (i & 3) * 16 + (i >> 2) * 128 + (q4 << 2);
#pragma unroll
      for (int r = 0; r < 4; ++r) {
        const int row = rbase + r;
        const float v = w_s[row] * (acc[i][j][r] + bias);
        if (EPI == 1) {
          scratch[(size_t)(sbase + m0 + row) * HD + col] = (_Float16)v;
        } else {
          if (m0 + row < ce)
            atomicAdd(&out[(size_t)tok_s[row] * HD + col], v);
        }
      }
    }
  }
}

// ---- Combine: out[t] = scratch[slot0] + scratch[slot1] ----
__global__ void moe_combine(const _Float16* __restrict__ scratch,
                            const int* __restrict__ slot_of,
                            float* __restrict__ out) {
  const int tid = threadIdx.x;
  const int t = blockIdx.x * 2 + (tid >> 7);
  const int c = (tid & 127) * 8;
  int sa = slot_of[2 * t], sb = slot_of[2 * t + 1];
  half8 a = *(const half8*)&scratch[(size_t)sa * HD + c];
  half8 b = *(const half8*)&scratch[(size_t)sb * HD + c];
  float* o = out + (size_t)t * HD + c;
  float4 o0 = {(float)a[0] + (float)b[0], (float)a[1] + (float)b[1],
               (float)a[2] + (float)b[2], (float)a[3] + (float)b[3]};
  float4 o1 = {(float)a[4] + (float)b[4], (float)a[5] + (float)b[5],
               (float)a[6] + (float)b[6], (float)a[7] + (float)b[7]};
  *(float4*)o = o0;
  *(float4*)(o + 4) = o1;
}

extern "C" void kernel_launch(void* const* d_in, const int* in_sizes, int n_in,
                              void* d_out, int out_size, void* d_ws, size_t ws_size,
                              hipStream_t stream) {
  (void)in_sizes; (void)n_in;
  const float* x  = (const float*)d_in[0];
  const float* rw = (const float*)d_in[1];
  const float* rb = (const float*)d_in[2];
  const float* ew = (const float*)d_in[3];
  const float* eb = (const float*)d_in[4];
  float* out = (float*)d_out;

  // ws layout
  char* w = (char*)d_ws;
  int*   cntp     = (int*)(w + 0);        // NE*64 ints (2 KB)
  int*   basep    = (int*)(w + 2048);     // 8 ints
  int*   hist     = (int*)(w + 2304);     // NE*NGRP ints (16 KB)
  size_t off = 2304 + (size_t)NE * NGRP * 4;
  int*   tok_list = (int*)(w + off);  off += (size_t)SLOTS * 4;
  float* tok_w    = (float*)(w + off); off += (size_t)SLOTS * 4;
  int*   slot_of  = (int*)(w + off);  off += (size_t)TOK * 8;
  int*   epair    = (int*)(w + off);  off += (size_t)TOK * 4;
  float* w1buf    = (float*)(w + off); off += (size_t)TOK * 4;
  off = (off + 255) & ~255ull;
  size_t xh_off = off;
  size_t wh_off = xh_off + (size_t)TOK * HD * 2;
  size_t scr_off = wh_off + (size_t)NE * HD * HD * 2;
  size_t needscr = scr_off + (size_t)SLOTS * HD * 2;
  bool fastscr = ws_size >= needscr;

  if (!fastscr)
    hipMemsetAsync(d_out, 0, (size_t)out_size * sizeof(float), stream);

  _Float16* xh = (_Float16*)(w + xh_off);
  _Float16* wh = (_Float16*)(w + wh_off);
  _Float16* scr = fastscr ? (_Float16*)(w + scr_off) : nullptr;

  score_cvt<<<NGRP + 2048, 256, 0, stream>>>(x, rw, rb, ew, xh, wh,
                                             epair, w1buf, hist);
  moe_scatter<<<NGRP, 256, 0, stream>>>(hist, epair, w1buf, cntp, basep,
                                        tok_list, tok_w, slot_of);

  // grid: x = n-tile (4), y = e*64 + mt; XCD = (4*mt + x) % 8 -> uniform.
  // Early-out on m0 >= ce keeps robustness for any expert skew.
  dim3 grid(HD / 256, NE * 64, 1);
  if (fastscr) {
    moe_gemm<1><<<grid, 512, 0, stream>>>(xh, wh, eb, cntp, basep,
                                          tok_list, tok_w, scr, out);
    moe_combine<<<TOK / 2, 256, 0, stream>>>(scr, slot_of, out);
  } else {
    moe_gemm<0><<<grid, 512, 0, stream>>>(xh, wh, eb, cntp, basep,
                                          tok_list, tok_w, nullptr, out);
  }
}

// Round 7
// 182.960 us; speedup vs baseline: 1.0753x; 1.0753x over previous
//
#include <hip/hip_runtime.h>
#include <hip/hip_bf16.h>
#include <math.h>

// MoE top-2: B=4,S=2048,H=1024,E=8,K=2. fp32 in/out, f16 MFMA compute.
#define TOK 8192
#define HD 1024
#define NE 8
#define SLOTS 17408     // 16384 + per-expert 128-pad
#define NGRP 512        // 16-token scatter groups
#define GRPSZ 16

typedef _Float16 half8 __attribute__((ext_vector_type(8)));
typedef _Float16 half4v __attribute__((ext_vector_type(4)));
typedef float floatx4 __attribute__((ext_vector_type(4)));

// ---- Fused score + weight-convert (block-role split) ----
__global__ __launch_bounds__(256) void score_cvt(
    const float* __restrict__ x,
    const float* __restrict__ rw,
    const float* __restrict__ rb,
    const float* __restrict__ ew,
    _Float16* __restrict__ xh,
    _Float16* __restrict__ wh,
    int* __restrict__ epair,
    float* __restrict__ w1out,
    int* __restrict__ hist) {          // [NE][NGRP]
  const int tid = threadIdx.x;
  const int blk = blockIdx.x;
  if (blk >= NGRP) {
    const int g = (blk - NGRP) * 256 + tid;
    const float4* src = (const float4*)ew;
    half4v* dst = (half4v*)wh;
#pragma unroll
    for (int j = 0; j < 4; ++j) {
      float4 v = src[g + 524288 * j];
      half4v h = {(_Float16)v.x, (_Float16)v.y, (_Float16)v.z, (_Float16)v.w};
      dst[g + 524288 * j] = h;
    }
    return;
  }
  const int lane = tid & 63;
  const int wid = tid >> 6;
  __shared__ int hcnt[NE];
  if (tid < NE) hcnt[tid] = 0;
  __syncthreads();

#pragma unroll
  for (int i = 0; i < 4; ++i) {
    const int t = blk * GRPSZ + wid * 4 + i;
    const float4* xp = (const float4*)(x + (size_t)t * HD);
    float4 xr[4];
#pragma unroll
    for (int k = 0; k < 4; ++k) xr[k] = xp[lane + 64 * k];
    _Float16* xo = xh + (size_t)t * HD;
#pragma unroll
    for (int k = 0; k < 4; ++k) {
      half4v h = {(_Float16)xr[k].x, (_Float16)xr[k].y,
                  (_Float16)xr[k].z, (_Float16)xr[k].w};
      *(half4v*)(xo + (lane + 64 * k) * 4) = h;
    }
    float sc[NE];
#pragma unroll
    for (int e = 0; e < NE; ++e) {
      const float4* wp = (const float4*)(rw + e * HD);
      float a = 0.f;
#pragma unroll
      for (int k = 0; k < 4; ++k) {
        float4 w = wp[lane + 64 * k];
        a += xr[k].x * w.x + xr[k].y * w.y + xr[k].z * w.z + xr[k].w * w.w;
      }
#pragma unroll
      for (int off = 32; off > 0; off >>= 1) a += __shfl_xor(a, off);
      sc[e] = a + rb[e];
    }
    // top-2, strict > (ties -> lowest index, matches jax.lax.top_k)
    float b1 = sc[0]; int e1 = 0;
#pragma unroll
    for (int e = 1; e < NE; ++e) if (sc[e] > b1) { b1 = sc[e]; e1 = e; }
    float b2 = -1e30f; int e2 = 0;
#pragma unroll
    for (int e = 0; e < NE; ++e) { if (e != e1 && sc[e] > b2) { b2 = sc[e]; e2 = e; } }
    if (lane == 0) {
      epair[t] = e1 | (e2 << 8);
      w1out[t] = 1.f / (1.f + expf(b2 - b1));  // renormalized top-2 softmax
      atomicAdd(&hcnt[e1], 1);
      atomicAdd(&hcnt[e2], 1);
    }
  }
  __syncthreads();
  if (tid < NE) hist[tid * NGRP + blk] = hcnt[tid];
}

// ---- Scatter: each block recomputes its prefix from hist (no global sync) --
__global__ __launch_bounds__(256) void moe_scatter(
    const int* __restrict__ hist,
    const int* __restrict__ epair,
    const float* __restrict__ w1in,
    int* __restrict__ cntp,
    int* __restrict__ basep,
    int* __restrict__ tok_list,
    float* __restrict__ tok_w,
    int* __restrict__ slot_of) {
  const int tid = threadIdx.x;
  const int blk = blockIdx.x;
  __shared__ int pre_s[NE], tot_s[NE], alloc_s[NE];
  {
    const int e = tid >> 5;
    const int sl = tid & 31;
    int p = 0, tt = 0;
#pragma unroll
    for (int j = 0; j < 16; ++j) {
      int g = sl + 32 * j;
      int h = hist[e * NGRP + g];
      tt += h;
      p += (g < blk) ? h : 0;
    }
#pragma unroll
    for (int off = 16; off > 0; off >>= 1) {
      p += __shfl_xor(p, off);
      tt += __shfl_xor(tt, off);
    }
    if (sl == 0) { pre_s[e] = p; tot_s[e] = tt; }
  }
  __syncthreads();
  if (tid == 0) {
    int b = 0;
    for (int e = 0; e < NE; ++e) {
      alloc_s[e] = b + pre_s[e];
      if (blk == 0) { cntp[e * 64] = tot_s[e]; basep[e] = b; }
      b += (tot_s[e] + 127) & ~127;
    }
  }
  __syncthreads();
  if (tid < GRPSZ) {
    const int t = blk * GRPSZ + tid;
    int ep = epair[t];
    int e1 = ep & 0xff, e2 = ep >> 8;
    float w1 = w1in[t];
    int s1 = atomicAdd(&alloc_s[e1], 1);
    tok_list[s1] = t; tok_w[s1] = w1; slot_of[2 * t] = s1;
    int s2 = atomicAdd(&alloc_s[e2], 1);
    tok_list[s2] = t; tok_w[s2] = 1.f - w1; slot_of[2 * t + 1] = s2;
  }
}

// ---- Grouped expert GEMM: 128x128 tile, BK=64, SINGLE-buffer, 4 blocks/CU.
// R6 decision: the m97 structure's throughput comes from CROSS-BLOCK wave
// overlap (m114), not intra-wave pipelining (R1->R2 dbuf+counted-vmcnt = 0).
// Our double buffer cost 34 KB LDS -> 2 blocks/CU; m97 ran ~3 blocks/CU at
// 874 TF. Single-buffer BK=64: LDS = 16+16 KB + 1.5 KB = 33.8 KB ->
// 4 blocks/CU, 16 waves/CU (4 waves/SIMD; VGPR 88*4=352<512).
// Loop = m97: stage -> syncthreads (drain) -> compute -> syncthreads; the
// drain stall is hidden by the other 3 resident blocks' MFMA waves.
// Pinning kept from R5 (FETCH 81->37 MB verified, timing-neutral): per XCD
// an expert's full ~128-block tile set is exactly co-resident (32 CU x 4).
// 3-bit XOR chunk swizzle: chunk g of row r at pos g^(r&7); reads pos
// cc^(l15&7) -> <=2-way bank aliasing (0 conflicts measured all rounds).
// EPI=1: f16 store to compacted scratch; EPI=0: fp32 atomicAdd to out.
template <int EPI>
__global__ __launch_bounds__(256, 4) void moe_gemm(
    const _Float16* __restrict__ Ah, const _Float16* __restrict__ Bh,
    const float* __restrict__ eb,
    const int* __restrict__ cntp, const int* __restrict__ base,
    const int* __restrict__ tok_list, const float* __restrict__ tok_w,
    _Float16* __restrict__ scratch, float* __restrict__ out) {
  const int e = blockIdx.x;                 // expert == XCD id
  const int ce = cntp[e * 64];
  const int mt = blockIdx.y >> 3;           // m-tile (0..63)
  const int m0 = mt << 7;
  if (m0 >= ce) return;
  const int n0 = (blockIdx.y & 7) << 7;     // n-tile
  const int sbase = base[e];
  const int tid = threadIdx.x;
  const int lane = tid & 63;
  const int wid = tid >> 6;
  const int wm = wid & 1, wn = wid >> 1;

  __shared__ _Float16 A_s[128 * 64];
  __shared__ _Float16 B_s[128 * 64];
  __shared__ int tok_s[128];
  __shared__ float w_s[128];

  if (tid < 128) {
    int tk = 0; float w = 0.f;
    if (m0 + tid < ce) { tk = tok_list[sbase + m0 + tid]; w = tok_w[sbase + m0 + tid]; }
    tok_s[tid] = tk; w_s[tid] = w;
  }
  __syncthreads();

  floatx4 acc[4][4];
  floatx4 zero = {0.f, 0.f, 0.f, 0.f};
#pragma unroll
  for (int i = 0; i < 4; ++i)
#pragma unroll
    for (int j = 0; j < 4; ++j) acc[i][j] = zero;

  const int wbase = e * HD * HD;   // fits int: <= 7*2^20
  // staging: 4 instrs/wave for A (+4 for B); each instr = 8 rows x 8 chunks.
  const int rloc = lane >> 3, sub = lane & 7;
  int agoff[4], bgoff[4];
#pragma unroll
  for (int q = 0; q < 4; ++q) {
    int row = wid * 32 + q * 8 + rloc;
    int g = sub ^ (row & 7);
    agoff[q] = tok_s[row] * HD + g * 8;
    bgoff[q] = wbase + (n0 + row) * HD + g * 8;
  }
  const int l15 = lane & 15, q4 = lane >> 4;

  auto stage = [&](int k0) {
#pragma unroll
    for (int q = 0; q < 4; ++q) {
      const int r0 = wid * 32 + q * 8;
      __builtin_amdgcn_global_load_lds(
          (const __attribute__((address_space(1))) unsigned int*)(Ah + agoff[q] + k0),
          (__attribute__((address_space(3))) unsigned int*)&A_s[r0 * 64], 16, 0, 0);
      __builtin_amdgcn_global_load_lds(
          (const __attribute__((address_space(1))) unsigned int*)(Bh + bgoff[q] + k0),
          (__attribute__((address_space(3))) unsigned int*)&B_s[r0 * 64], 16, 0, 0);
    }
  };

  auto compute = [&]() {
#pragma unroll
    for (int kf = 0; kf < 2; ++kf) {
      half8 afr[4], bfr[4];
      const int cc = kf * 4 + q4;
#pragma unroll
      for (int i = 0; i < 4; ++i)
        afr[i] = *(const half8*)&A_s[(wm * 64 + i * 16 + l15) * 64 + ((cc ^ (l15 & 7)) * 8)];
#pragma unroll
      for (int j = 0; j < 4; ++j)
        bfr[j] = *(const half8*)&B_s[(wn * 64 + j * 16 + l15) * 64 + ((cc ^ (l15 & 7)) * 8)];
#pragma unroll
      for (int i = 0; i < 4; ++i)
#pragma unroll
        for (int j = 0; j < 4; ++j)
          acc[i][j] = __builtin_amdgcn_mfma_f32_16x16x32_f16(afr[i], bfr[j], acc[i][j], 0, 0, 0);
    }
  };

  // K-loop: 16 steps of BK=64, single-buffered m97 loop. The syncthreads
  // drain is hidden by the other 3 co-resident blocks on this CU (TLP).
  for (int t = 0; t < 16; ++t) {
    stage(t * 64);
    __syncthreads();
    compute();
    __syncthreads();
  }

  // epilogue: C/D layout col=lane&15, row=(lane>>4)*4+reg
#pragma unroll
  for (int j = 0; j < 4; ++j) {
    int col = n0 + wn * 64 + j * 16 + l15;
    float bias = eb[e * HD + col];
#pragma unroll
    for (int i = 0; i < 4; ++i) {
      int rbase = wm * 64 + i * 16 + (q4 << 2);
#pragma unroll
      for (int r = 0; r < 4; ++r) {
        int row = rbase + r;
        float v = w_s[row] * (acc[i][j][r] + bias);
        if (EPI == 1) {
          scratch[(size_t)(sbase + m0 + row) * HD + col] = (_Float16)v;
        } else {
          if (m0 + row < ce)
            atomicAdd(&out[(size_t)tok_s[row] * HD + col], v);
        }
      }
    }
  }
}

// ---- Combine: out[t] = scratch[slot0] + scratch[slot1] ----
__global__ void moe_combine(const _Float16* __restrict__ scratch,
                            const int* __restrict__ slot_of,
                            float* __restrict__ out) {
  const int tid = threadIdx.x;
  const int t = blockIdx.x * 2 + (tid >> 7);
  const int c = (tid & 127) * 8;
  int sa = slot_of[2 * t], sb = slot_of[2 * t + 1];
  half8 a = *(const half8*)&scratch[(size_t)sa * HD + c];
  half8 b = *(const half8*)&scratch[(size_t)sb * HD + c];
  float* o = out + (size_t)t * HD + c;
  float4 o0 = {(float)a[0] + (float)b[0], (float)a[1] + (float)b[1],
               (float)a[2] + (float)b[2], (float)a[3] + (float)b[3]};
  float4 o1 = {(float)a[4] + (float)b[4], (float)a[5] + (float)b[5],
               (float)a[6] + (float)b[6], (float)a[7] + (float)b[7]};
  *(float4*)o = o0;
  *(float4*)(o + 4) = o1;
}

extern "C" void kernel_launch(void* const* d_in, const int* in_sizes, int n_in,
                              void* d_out, int out_size, void* d_ws, size_t ws_size,
                              hipStream_t stream) {
  (void)in_sizes; (void)n_in;
  const float* x  = (const float*)d_in[0];
  const float* rw = (const float*)d_in[1];
  const float* rb = (const float*)d_in[2];
  const float* ew = (const float*)d_in[3];
  const float* eb = (const float*)d_in[4];
  float* out = (float*)d_out;

  // ws layout
  char* w = (char*)d_ws;
  int*   cntp     = (int*)(w + 0);        // NE*64 ints (2 KB)
  int*   basep    = (int*)(w + 2048);     // 8 ints
  int*   hist     = (int*)(w + 2304);     // NE*NGRP ints (16 KB)
  size_t off = 2304 + (size_t)NE * NGRP * 4;
  int*   tok_list = (int*)(w + off);  off += (size_t)SLOTS * 4;
  float* tok_w    = (float*)(w + off); off += (size_t)SLOTS * 4;
  int*   slot_of  = (int*)(w + off);  off += (size_t)TOK * 8;
  int*   epair    = (int*)(w + off);  off += (size_t)TOK * 4;
  float* w1buf    = (float*)(w + off); off += (size_t)TOK * 4;
  off = (off + 255) & ~255ull;
  size_t xh_off = off;
  size_t wh_off = xh_off + (size_t)TOK * HD * 2;
  size_t scr_off = wh_off + (size_t)NE * HD * HD * 2;
  size_t needscr = scr_off + (size_t)SLOTS * HD * 2;
  bool fastscr = ws_size >= needscr;

  if (!fastscr)
    hipMemsetAsync(d_out, 0, (size_t)out_size * sizeof(float), stream);

  _Float16* xh = (_Float16*)(w + xh_off);
  _Float16* wh = (_Float16*)(w + wh_off);
  _Float16* scr = fastscr ? (_Float16*)(w + scr_off) : nullptr;

  score_cvt<<<NGRP + 2048, 256, 0, stream>>>(x, rw, rb, ew, xh, wh,
                                             epair, w1buf, hist);
  moe_scatter<<<NGRP, 256, 0, stream>>>(hist, epair, w1buf, cntp, basep,
                                        tok_list, tok_w, slot_of);

  // grid: x = expert (= XCD id), y = mt*8 + nt (64 m-tiles x 8 n-tiles);
  // early-out on m0 >= ce. ~128 live blocks/XCD = 32 CUs x 4 blocks/CU.
  dim3 grid(NE, 512, 1);
  if (fastscr) {
    moe_gemm<1><<<grid, 256, 0, stream>>>(xh, wh, eb, cntp, basep,
                                          tok_list, tok_w, scr, out);
    moe_combine<<<TOK / 2, 256, 0, stream>>>(scr, slot_of, out);
  } else {
    moe_gemm<0><<<grid, 256, 0, stream>>>(xh, wh, eb, cntp, basep,
                                          tok_list, tok_w, nullptr, out);
  }
}